// Round 11
// baseline (203.768 us; speedup 1.0000x reference)
//
#include <hip/hip_runtime.h>

// StandGCN2: 2-layer GCN, N=100000, E=600000, 128->128(relu)->64, bf16 I/O.
// R17 (resubmit; R10's bench was GPUAcquisitionTimeout - no data): de-LDS the
// gemm role. R16 measured nbgemm=40.8us with Occ 12.4%, VALU 10%, hbm 18% -
// latency-bound: 34.8KB Wt LDS capped 4 blocks/CU and the 708-block grid
// delivered ~2.8. Fix: W1 is 32KB -> prep writes W1^T (transposed, same as
// W2t) and gemm reads B-fragments DIRECT from global (L1/L2-resident; B
// traffic ~200MB from L2 @37TB/s = 5us, not a constraint). Deletes Wt
// staging + barrier + LDS footprint -> LDS=6KB (nbuild's), occupancy
// VGPR-limited ~20 waves/CU; GEMMB 512->1024 to fill the machine.
// fusedB/agg2 remain the R12-proven forms.
// Pipeline (5 kernels + 2KB memset): memset(bhist,boff) -> prep_hist -> part
// -> nbgemm(nbuild || gemm1) -> fusedB -> agg2.

typedef unsigned short u16;
typedef unsigned int u32;
typedef __attribute__((ext_vector_type(8))) short bf16x8;
typedef __attribute__((ext_vector_type(4))) float f32x4;

#define BSH 9                  // bucket shift: 512 nodes/bucket
#define BMSK ((1 << BSH) - 1)
#define MAXBK 256              // max buckets supported (N <= 131072)
#define SEG 2560               // edges per part_k block (LDS-staged)
#define HISTB 128              // histogram blocks
#define GEMMB 1024             // gemm role blocks in nbgemm

__device__ __forceinline__ u16 f2b(float f) {
  u32 u = __float_as_uint(f);
  u32 r = (u + 0x7FFFu + ((u >> 16) & 1u)) >> 16;
  return (u16)r;
}
__device__ __forceinline__ u32 pk2(float a, float b) {
  return (u32)f2b(a) | ((u32)f2b(b) << 16);
}
__device__ __forceinline__ void dec8(uint4 v, float f[8]) {
  f[0] = __uint_as_float(v.x << 16);
  f[1] = __uint_as_float(v.x & 0xFFFF0000u);
  f[2] = __uint_as_float(v.y << 16);
  f[3] = __uint_as_float(v.y & 0xFFFF0000u);
  f[4] = __uint_as_float(v.z << 16);
  f[5] = __uint_as_float(v.z & 0xFFFF0000u);
  f[6] = __uint_as_float(v.w << 16);
  f[7] = __uint_as_float(v.w & 0xFFFF0000u);
}
__device__ __forceinline__ void fma8(uint4 v, float d, float acc[8]) {
  acc[0] = fmaf(__uint_as_float(v.x << 16), d, acc[0]);
  acc[1] = fmaf(__uint_as_float(v.x & 0xFFFF0000u), d, acc[1]);
  acc[2] = fmaf(__uint_as_float(v.y << 16), d, acc[2]);
  acc[3] = fmaf(__uint_as_float(v.y & 0xFFFF0000u), d, acc[3]);
  acc[4] = fmaf(__uint_as_float(v.z << 16), d, acc[4]);
  acc[5] = fmaf(__uint_as_float(v.z & 0xFFFF0000u), d, acc[5]);
  acc[6] = fmaf(__uint_as_float(v.w << 16), d, acc[6]);
  acc[7] = fmaf(__uint_as_float(v.w & 0xFFFF0000u), d, acc[7]);
}

// ---- prep_hist: [0,PREPB) prep (probe + weight convert, W1 TRANSPOSED);
//      [PREPB,PREPB+HISTB) bucket histogram (LDS, then <=NBK global adds/block) ----

__global__ __launch_bounds__(256) void prep_hist_k(const void* __restrict__ W1,
                                                   const void* __restrict__ b1,
                                                   const void* __restrict__ W2,
                                                   const void* __restrict__ b2,
                                                   u16* __restrict__ W1t, u16* __restrict__ ob1,
                                                   u16* __restrict__ W2t, u16* __restrict__ ob2,
                                                   int* __restrict__ mode,
                                                   const int* __restrict__ dst,
                                                   int* __restrict__ bhist,
                                                   int E, int PREPB) {
  const int tid = threadIdx.x;

  if ((int)blockIdx.x >= PREPB) {
    __shared__ int lh[MAXBK];
    const int hb = (int)blockIdx.x - PREPB;
    for (int j = tid; j < MAXBK; j += 256) lh[j] = 0;
    __syncthreads();
    const int chunk = (E + HISTB - 1) / HISTB;
    const int e0 = hb * chunk;
    const int e1 = min(E, e0 + chunk);
    for (int e = e0 + tid; e < e1; e += 256) atomicAdd(&lh[dst[e] >> BSH], 1);
    __syncthreads();
    for (int j = tid; j < MAXBK; j += 256) {
      int v = lh[j];
      if (v) atomicAdd(&bhist[j], v);
    }
    return;
  }

  // prep role: block-local dtype probe + weight convert
  __shared__ int cnt_s;
  if (tid == 0) cnt_s = 0;
  __syncthreads();
  int c = 0;
  for (int j = tid; j < 4096; j += 256) {
    u32 e = (((const u16*)W1)[j] >> 7) & 0xFFu;
    if (e >= 100u && e <= 130u) c++;
  }
  atomicAdd(&cnt_s, c);
  __syncthreads();
  const int m = (cnt_s < 3328) ? 1 : 0;  // 1 = fp32
  if (blockIdx.x == 0 && tid == 0) *mode = m;

  int i = blockIdx.x * 256 + tid;
  if (i < 24768) {
    int j = i;
    const void* src;
    u16* dstp;
    int sidx, didx;
    if (j < 16384) {
      int nn = j >> 7, k = j & 127;               // W1t[n][k] = W1[k][n]
      src = W1; dstp = W1t; sidx = k * 128 + nn; didx = j;
    } else if ((j -= 16384) < 128) {
      src = b1; dstp = ob1; sidx = j; didx = j;
    } else if ((j -= 128) < 8192) {
      int nn = j >> 7, k = j & 127;               // W2t[n][k] = W2[k][n]
      src = W2; dstp = W2t; sidx = k * 64 + nn; didx = j;
    } else {
      j -= 8192;
      src = b2; dstp = ob2; sidx = j; didx = j;
    }
    dstp[didx] = m ? f2b(((const float*)src)[sidx]) : ((const u16*)src)[sidx];
  }
}

// ---- part_k: radix partition edges by dst bucket into tmp (sequential runs) ----

__global__ __launch_bounds__(256) void part_k(const int* __restrict__ src,
                                              const int* __restrict__ dst,
                                              const int* __restrict__ bhist,
                                              int* __restrict__ boff,
                                              int2* __restrict__ tmp,
                                              int E, int NBK) {
  __shared__ int ls[SEG];
  __shared__ int ld_[SEG];
  __shared__ int lh[MAXBK];
  __shared__ int base_[MAXBK];
  __shared__ int bsl[MAXBK];
  const int tid = threadIdx.x;

  // exclusive scan of bhist -> bsl (256 threads, 256 entries)
  int ov = (tid < NBK) ? bhist[tid] : 0;
  bsl[tid] = ov;
  __syncthreads();
#pragma unroll
  for (int off = 1; off < 256; off <<= 1) {
    int add = (tid >= off) ? bsl[tid - off] : 0;
    __syncthreads();
    bsl[tid] += add;
    __syncthreads();
  }
  bsl[tid] -= ov;  // exclusive
  if (tid < MAXBK) lh[tid] = 0;
  __syncthreads();

  const int e0 = blockIdx.x * SEG;
  const int len = min(SEG, E - e0);
  for (int j = tid; j < len; j += 256) {
    int s = src[e0 + j];
    int d = dst[e0 + j];
    ls[j] = s;
    ld_[j] = d;
    atomicAdd(&lh[d >> BSH], 1);
  }
  __syncthreads();
  if (tid < NBK) {
    int hh = lh[tid];
    base_[tid] = hh ? bsl[tid] + atomicAdd(&boff[tid], hh) : 0;
    lh[tid] = 0;  // reuse as rank counter
  }
  __syncthreads();
  for (int j = tid; j < len; j += 256) {
    int d = ld_[j];
    int bk = d >> BSH;
    int r = atomicAdd(&lh[bk], 1);
    tmp[base_[bk] + r] = make_int2(ls[j], d);
  }
}

// ---- nbgemm: [0,NBK) nbuild role; [NBK,NBK+GEMMB) gemm role ----
// nbuild: one block per bucket, 6KB LDS (count/scan/scatter).
// gemm:   h = x @ W1. A-fragments direct from global (contiguous 16B of x
//         row); B-fragments direct from global W1t (32KB, L1/L2-resident).
//         No LDS, no barrier. Layouts (m89/m91): A[m=lane&15][k=(lane>>4)*8+j];
//         C/D col=lane&15, row=(lane>>4)*4+reg.

__global__ __launch_bounds__(256) void nbgemm_k(const int2* __restrict__ tmp,
                                                const int* __restrict__ bhist,
                                                float* __restrict__ dinv,
                                                int4* __restrict__ ninfo,
                                                int* __restrict__ spI,
                                                int np, int NBK,
                                                const void* __restrict__ Araw,
                                                const u16* __restrict__ Wt,
                                                u16* __restrict__ hout, int M,
                                                const int* __restrict__ mode) {
  __shared__ int bsl[MAXBK];
  __shared__ int cntl[1 << BSH];
  __shared__ int curl[1 << BSH];
  __shared__ int sc2[256];
  const int tid = threadIdx.x;

  if ((int)blockIdx.x < NBK) {
    // ---------------- nbuild role ----------------
    const int b = blockIdx.x;

    // exclusive scan of bhist -> bsl
    int ov = (tid < NBK) ? bhist[tid] : 0;
    bsl[tid] = ov;
    __syncthreads();
#pragma unroll
    for (int off = 1; off < 256; off <<= 1) {
      int add = (tid >= off) ? bsl[tid - off] : 0;
      __syncthreads();
      bsl[tid] += add;
      __syncthreads();
    }
    bsl[tid] -= ov;
    cntl[tid] = 0;
    cntl[tid + 256] = 0;
    curl[tid] = 0;
    curl[tid + 256] = 0;
    __syncthreads();

    const int bs = bsl[b];
    const int be = bs + bhist[b];
    const int lo = b << BSH;

    // pass 1: per-node count (LDS atomics)
    for (int e = bs + tid; e < be; e += 256) {
      int2 p = tmp[e];
      atomicAdd(&cntl[p.y & BMSK], 1);
    }
    __syncthreads();

    // scan 512 with 256 threads (2 elems/thread)
    const int c0 = cntl[2 * tid];
    const int c1 = cntl[2 * tid + 1];
    const int s2 = c0 + c1;
    sc2[tid] = s2;
    __syncthreads();
#pragma unroll
    for (int off = 1; off < 256; off <<= 1) {
      int add = (tid >= off) ? sc2[tid - off] : 0;
      __syncthreads();
      sc2[tid] += add;
      __syncthreads();
    }
    const int excl = sc2[tid] - s2;
    const int e0n = excl;
    const int e1n = excl + c0;

    {
      int i0 = lo + 2 * tid;
      if (i0 < np) {
        float dv = rsqrtf((float)c0 + 1.0f);
        dinv[i0] = dv;
        ninfo[i0] = make_int4(bs + e0n, c0, __float_as_int(dv), 0);
      }
      int i1 = i0 + 1;
      if (i1 < np) {
        float dv = rsqrtf((float)c1 + 1.0f);
        dinv[i1] = dv;
        ninfo[i1] = make_int4(bs + e1n, c1, __float_as_int(dv), 0);
      }
    }
    cntl[2 * tid] = e0n;
    cntl[2 * tid + 1] = e1n;
    __syncthreads();

    // pass 2: scatter src into sp at node offsets (LDS rank)
    for (int e = bs + tid; e < be; e += 256) {
      int2 p = tmp[e];
      int loc = p.y & BMSK;
      int r = atomicAdd(&curl[loc], 1);
      spI[bs + cntl[loc] + r] = p.x;
    }
    return;
  }

  // ---------------- gemm role (no LDS, no barrier) ----------------
  const int mcv = *mode;
  const int wv = tid >> 6, lane = tid & 63, lr = lane & 15, lq = lane >> 4;
  const int ntiles = (M + 63) >> 6;

  for (int t = (int)blockIdx.x - NBK; t < ntiles; t += GEMMB) {
    const int r0 = t * 64;
    const int arow = r0 + wv * 16 + lr;
    const bool rok = (arow < M);

    bf16x8 a[4];
    if (mcv) {
      const float* xr = (const float*)Araw + (size_t)arow * 128 + lq * 8;
#pragma unroll
      for (int s = 0; s < 4; ++s) {
        uint4 u = make_uint4(0u, 0u, 0u, 0u);
        if (rok) {
          float4 f0 = *(const float4*)(xr + s * 32);
          float4 f1 = *(const float4*)(xr + s * 32 + 4);
          u.x = pk2(f0.x, f0.y);
          u.y = pk2(f0.z, f0.w);
          u.z = pk2(f1.x, f1.y);
          u.w = pk2(f1.z, f1.w);
        }
        a[s] = *(const bf16x8*)&u;
      }
    } else {
      const u16* xr = (const u16*)Araw + (size_t)arow * 128 + lq * 8;
#pragma unroll
      for (int s = 0; s < 4; ++s) {
        uint4 u = rok ? *(const uint4*)(xr + s * 32) : make_uint4(0u, 0u, 0u, 0u);
        a[s] = *(const bf16x8*)&u;
      }
    }

#pragma unroll
    for (int nt = 0; nt < 8; ++nt) {
      f32x4 acc = {0.f, 0.f, 0.f, 0.f};
#pragma unroll
      for (int s = 0; s < 4; ++s) {
        bf16x8 b = *(const bf16x8*)&Wt[(size_t)(nt * 16 + lr) * 128 + s * 32 + lq * 8];
        acc = __builtin_amdgcn_mfma_f32_16x16x32_bf16(a[s], b, acc, 0, 0, 0);
      }
#pragma unroll
      for (int r = 0; r < 4; ++r) {
        int row = r0 + wv * 16 + lq * 4 + r;
        if (row < M) hout[(size_t)row * 128 + nt * 16 + lr] = f2b(acc[r]);
      }
    }
  }
}

// ---- fusedB: gather-aggregate h (16 nodes/block, quarter-wave, unroll-4)
//      -> +b1, relu -> LDS tile -> MFMA W2t -> g[N,64] ----   (R12-proven)

__global__ __launch_bounds__(256) void fusedB_k(const u16* __restrict__ h,
                                                const int* __restrict__ spI,
                                                const int4* __restrict__ ninfo,
                                                const float* __restrict__ dinv,
                                                const u16* __restrict__ b1,
                                                const u16* __restrict__ W2t,
                                                u16* __restrict__ g, int n) {
  __shared__ __align__(16) u16 As[16 * 136];
  const int tid = threadIdx.x, wv = tid >> 6, lane = tid & 63;
  const int lq = lane >> 4, lr = lane & 15;
  const int base = blockIdx.x * 16;
  const int i = base + wv * 4 + lq;
  const bool valid = (i < n);

  int start = 0, c = 0;
  float di = 0.f;
  if (valid) {
    int4 ni = ninfo[i];
    start = ni.x;
    c = ni.y;
    di = __int_as_float(ni.z);
  }
  float acc[8];
  {
    uint4 v = valid ? *(const uint4*)(h + (size_t)i * 128 + lr * 8)
                    : make_uint4(0u, 0u, 0u, 0u);
    float f[8];
    dec8(v, f);
#pragma unroll
    for (int j = 0; j < 8; ++j) acc[j] = f[j] * di;
  }
  const int bl = lq * 16;
  for (int bs = 0; __any(bs < c); bs += 16) {
    int m = c - bs;
    m = m < 0 ? 0 : (m > 16 ? 16 : m);
    int s = 0;
    float dv = 0.f;
    if (lr < m) {
      s = spI[start + bs + lr];
      dv = dinv[s];
    }
    int mmw = m;
    mmw = max(mmw, __shfl_xor(mmw, 16));
    mmw = max(mmw, __shfl_xor(mmw, 32));
    for (int e = 0; e < mmw; e += 4) {
      int s0 = __shfl(s, bl + e), s1 = __shfl(s, bl + e + 1);
      int s2 = __shfl(s, bl + e + 2), s3 = __shfl(s, bl + e + 3);
      float d0 = __shfl(dv, bl + e);
      float d1 = __shfl(dv, bl + e + 1);
      float d2 = __shfl(dv, bl + e + 2);
      float d3 = __shfl(dv, bl + e + 3);
      uint4 v0 = *(const uint4*)(h + (size_t)s0 * 128 + lr * 8);
      uint4 v1 = *(const uint4*)(h + (size_t)s1 * 128 + lr * 8);
      uint4 v2 = *(const uint4*)(h + (size_t)s2 * 128 + lr * 8);
      uint4 v3 = *(const uint4*)(h + (size_t)s3 * 128 + lr * 8);
      fma8(v0, d0, acc);
      fma8(v1, d1, acc);
      fma8(v2, d2, acc);
      fma8(v3, d3, acc);
    }
  }
  {
    uint4 bv = *(const uint4*)(b1 + lr * 8);
    float bf[8];
    dec8(bv, bf);
    float o[8];
#pragma unroll
    for (int j = 0; j < 8; ++j) o[j] = fmaxf(fmaf(acc[j], di, bf[j]), 0.f);
    uint4 ov;
    ov.x = pk2(o[0], o[1]);
    ov.y = pk2(o[2], o[3]);
    ov.z = pk2(o[4], o[5]);
    ov.w = pk2(o[6], o[7]);
    *(uint4*)&As[(wv * 4 + lq) * 136 + lr * 8] = ov;
  }
  __syncthreads();

  bf16x8 a[4];
#pragma unroll
  for (int s = 0; s < 4; ++s)
    a[s] = *(const bf16x8*)&As[lr * 136 + s * 32 + lq * 8];
  {
    const int nt = wv;
    f32x4 acc4 = {0.f, 0.f, 0.f, 0.f};
#pragma unroll
    for (int s = 0; s < 4; ++s) {
      bf16x8 b = *(const bf16x8*)&W2t[(nt * 16 + lr) * 128 + s * 32 + lq * 8];
      acc4 = __builtin_amdgcn_mfma_f32_16x16x32_bf16(a[s], b, acc4, 0, 0, 0);
    }
#pragma unroll
    for (int r = 0; r < 4; ++r) {
      int row = base + lq * 4 + r;
      if (row < n) g[(size_t)row * 64 + nt * 16 + lr] = f2b(acc4[r]);
    }
  }
}

// ---- agg2: oct-wave over g, 8 nodes/wave, unroll-4 ----   (R12-proven)

__global__ __launch_bounds__(256) void agg2_k(const u16* __restrict__ g,
                                              const int* __restrict__ spI,
                                              const int4* __restrict__ ninfo,
                                              const float* __restrict__ dinv,
                                              const u16* __restrict__ b2,
                                              void* __restrict__ outv, int n,
                                              const int* __restrict__ mode) {
  const int lane = threadIdx.x & 63;
  const int o8 = lane >> 3, l8 = lane & 7;
  const int i = blockIdx.x * 32 + (threadIdx.x >> 6) * 8 + o8;
  const bool valid = (i < n);

  int start = 0, c = 0;
  float di = 0.f;
  if (valid) {
    int4 ni = ninfo[i];
    start = ni.x;
    c = ni.y;
    di = __int_as_float(ni.z);
  }
  float acc[8];
  {
    uint4 v = valid ? *(const uint4*)(g + (size_t)i * 64 + l8 * 8)
                    : make_uint4(0u, 0u, 0u, 0u);
    float f[8];
    dec8(v, f);
#pragma unroll
    for (int j = 0; j < 8; ++j) acc[j] = f[j] * di;
  }
  const int bl = o8 * 8;
  for (int base = 0; __any(base < c); base += 8) {
    int m = c - base;
    m = m < 0 ? 0 : (m > 8 ? 8 : m);
    int s = 0;
    float dv = 0.f;
    if (l8 < m) {
      s = spI[start + base + l8];
      dv = dinv[s];
    }
    int mmw = m;
    mmw = max(mmw, __shfl_xor(mmw, 8));
    mmw = max(mmw, __shfl_xor(mmw, 16));
    mmw = max(mmw, __shfl_xor(mmw, 32));
    for (int e = 0; e < mmw; e += 4) {
      int s0 = __shfl(s, bl + e), s1 = __shfl(s, bl + e + 1);
      int s2 = __shfl(s, bl + e + 2), s3 = __shfl(s, bl + e + 3);
      float d0 = __shfl(dv, bl + e);
      float d1 = __shfl(dv, bl + e + 1);
      float d2 = __shfl(dv, bl + e + 2);
      float d3 = __shfl(dv, bl + e + 3);
      uint4 v0 = *(const uint4*)(g + (size_t)s0 * 64 + l8 * 8);
      uint4 v1 = *(const uint4*)(g + (size_t)s1 * 64 + l8 * 8);
      uint4 v2 = *(const uint4*)(g + (size_t)s2 * 64 + l8 * 8);
      uint4 v3 = *(const uint4*)(g + (size_t)s3 * 64 + l8 * 8);
      fma8(v0, d0, acc);
      fma8(v1, d1, acc);
      fma8(v2, d2, acc);
      fma8(v3, d3, acc);
    }
  }
  if (valid) {
    uint4 bv = *(const uint4*)(b2 + l8 * 8);
    float bf[8];
    dec8(bv, bf);
    float o[8];
#pragma unroll
    for (int j = 0; j < 8; ++j) o[j] = fmaf(acc[j], di, bf[j]);
    if (*mode) {
      float* op = (float*)outv + (size_t)i * 64 + l8 * 8;
      *(float4*)op = make_float4(o[0], o[1], o[2], o[3]);
      *(float4*)(op + 4) = make_float4(o[4], o[5], o[6], o[7]);
    } else {
      uint4 ov;
      ov.x = pk2(o[0], o[1]);
      ov.y = pk2(o[2], o[3]);
      ov.z = pk2(o[4], o[5]);
      ov.w = pk2(o[6], o[7]);
      *(uint4*)((u16*)outv + (size_t)i * 64 + l8 * 8) = ov;
    }
  }
}

// ================= launch =================

extern "C" void kernel_launch(void* const* d_in, const int* in_sizes, int n_in,
                              void* d_out, int out_size, void* d_ws, size_t ws_size,
                              hipStream_t stream) {
  const void* x_raw  = d_in[0];
  const int*  ei     = (const int*)d_in[1];
  const void* W1_raw = d_in[2];
  const void* b1_raw = d_in[3];
  const void* W2_raw = d_in[4];
  const void* b2_raw = d_in[5];

  const int N = in_sizes[0] / 128;
  const int E = in_sizes[1] / 2;
  const int NP = ((N + 255) / 256) * 256;
  const int NBK = (NP + (1 << BSH) - 1) >> BSH;   // buckets (<=256 for N<=131072)
  const int PREPB = (24768 + 255) / 256;          // 97 prep blocks

  char* ws = (char*)d_ws;
  size_t off = 0;
  auto alloc = [&](size_t bytes) -> void* {
    void* p = ws + off;
    off = (off + bytes + 255) & ~(size_t)255;
    return p;
  };
  int*   mode    = (int*)alloc(4);
  int*   bz      = (int*)alloc((size_t)2 * MAXBK * 4);  // bhist | boff
  int*   bhist   = bz;
  int*   boff    = bz + MAXBK;
  float* dinv    = (float*)alloc((size_t)NP * 4);
  int4*  ninfo   = (int4*)alloc((size_t)NP * 16);
  int*   spI     = (int*)alloc((size_t)E * 4);
  int2*  tmp     = (int2*)alloc((size_t)E * 8);
  u16*   W1t     = (u16*)alloc((size_t)128 * 128 * 2);
  u16*   b1b     = (u16*)alloc(128 * 2);
  u16*   W2t     = (u16*)alloc((size_t)64 * 128 * 2);
  u16*   b2b     = (u16*)alloc(64 * 2);
  u16*   h       = (u16*)alloc((size_t)N * 128 * 2);
  u16*   g       = (u16*)alloc((size_t)N * 64 * 2);

  const int pb = (E + SEG - 1) / SEG;

  hipMemsetAsync(bz, 0, (size_t)2 * MAXBK * 4, stream);
  prep_hist_k<<<PREPB + HISTB, 256, 0, stream>>>(W1_raw, b1_raw, W2_raw, b2_raw,
                                                 W1t, b1b, W2t, b2b, mode,
                                                 ei + E, bhist, E, PREPB);
  part_k<<<pb, 256, 0, stream>>>(ei, ei + E, bhist, boff, tmp, E, NBK);
  nbgemm_k<<<NBK + GEMMB, 256, 0, stream>>>(tmp, bhist, dinv, ninfo, spI, NP, NBK,
                                            x_raw, W1t, h, N, mode);
  fusedB_k<<<(N + 15) / 16, 256, 0, stream>>>(h, spI, ninfo, dinv, b1b, W2t, g, N);
  agg2_k<<<(N + 31) / 32, 256, 0, stream>>>(g, spI, ninfo, dinv, b2b, d_out, N, mode);
}

// Round 12
// 197.676 us; speedup vs baseline: 1.0308x; 1.0308x over previous
//
#include <hip/hip_runtime.h>

// StandGCN2: 2-layer GCN, N=100000, E=600000, 128->128(relu)->64, bf16 I/O.
// R18: pipeline reverted to R12 shape (separate nbuild; 194.4us measured);
// ONLY gemm1 restructured. Diagnosis: R12/R16/R17 gemm variants all ~40-45us
// at 1.3TB/s with nothing busy (Occ 15%, VALU 8%, Mfma 2.5%) - a serialized
// load->compute->store chain per tile. Fixes:
// (a) B in FRAGMENT-ORDERED global layout W1f[((nt*4+s)*64+lane)*8]: each
//     B-load is one coalesced 1KB wave-instruction, same addr for all 4
//     waves (L1 broadcast). No LDS, no barrier in gemm.
// (b) 2-deep A prefetch: block owns tiles {t, t+GEMMB}; A(t+1) loads issue
//     before tile t's MFMA/store phase -> load latency hidden under compute.
// Pipeline (6 kernels + 2KB memset): memset -> prep_hist -> part -> nbuild
// -> gemm1 -> fusedB -> agg2.

typedef unsigned short u16;
typedef unsigned int u32;
typedef __attribute__((ext_vector_type(8))) short bf16x8;
typedef __attribute__((ext_vector_type(4))) float f32x4;

#define BSH 9                  // bucket shift: 512 nodes/bucket
#define BMSK ((1 << BSH) - 1)
#define MAXBK 256              // max buckets supported (N <= 131072)
#define SEG 2560               // edges per part_k block (LDS-staged)
#define HISTB 128              // histogram blocks
#define GEMMB 784              // gemm blocks (~2 tiles each)

__device__ __forceinline__ u16 f2b(float f) {
  u32 u = __float_as_uint(f);
  u32 r = (u + 0x7FFFu + ((u >> 16) & 1u)) >> 16;
  return (u16)r;
}
__device__ __forceinline__ u32 pk2(float a, float b) {
  return (u32)f2b(a) | ((u32)f2b(b) << 16);
}
__device__ __forceinline__ void dec8(uint4 v, float f[8]) {
  f[0] = __uint_as_float(v.x << 16);
  f[1] = __uint_as_float(v.x & 0xFFFF0000u);
  f[2] = __uint_as_float(v.y << 16);
  f[3] = __uint_as_float(v.y & 0xFFFF0000u);
  f[4] = __uint_as_float(v.z << 16);
  f[5] = __uint_as_float(v.z & 0xFFFF0000u);
  f[6] = __uint_as_float(v.w << 16);
  f[7] = __uint_as_float(v.w & 0xFFFF0000u);
}
__device__ __forceinline__ void fma8(uint4 v, float d, float acc[8]) {
  acc[0] = fmaf(__uint_as_float(v.x << 16), d, acc[0]);
  acc[1] = fmaf(__uint_as_float(v.x & 0xFFFF0000u), d, acc[1]);
  acc[2] = fmaf(__uint_as_float(v.y << 16), d, acc[2]);
  acc[3] = fmaf(__uint_as_float(v.y & 0xFFFF0000u), d, acc[3]);
  acc[4] = fmaf(__uint_as_float(v.z << 16), d, acc[4]);
  acc[5] = fmaf(__uint_as_float(v.z & 0xFFFF0000u), d, acc[5]);
  acc[6] = fmaf(__uint_as_float(v.w << 16), d, acc[6]);
  acc[7] = fmaf(__uint_as_float(v.w & 0xFFFF0000u), d, acc[7]);
}

// ---- prep_hist: [0,PREPB) prep (probe + weight convert; W1 in FRAGMENT
//      order W1f); [PREPB,PREPB+HISTB) bucket histogram ----

__global__ __launch_bounds__(256) void prep_hist_k(const void* __restrict__ W1,
                                                   const void* __restrict__ b1,
                                                   const void* __restrict__ W2,
                                                   const void* __restrict__ b2,
                                                   u16* __restrict__ W1f, u16* __restrict__ ob1,
                                                   u16* __restrict__ W2t, u16* __restrict__ ob2,
                                                   int* __restrict__ mode,
                                                   const int* __restrict__ dst,
                                                   int* __restrict__ bhist,
                                                   int E, int PREPB) {
  const int tid = threadIdx.x;

  if ((int)blockIdx.x >= PREPB) {
    __shared__ int lh[MAXBK];
    const int hb = (int)blockIdx.x - PREPB;
    for (int j = tid; j < MAXBK; j += 256) lh[j] = 0;
    __syncthreads();
    const int chunk = (E + HISTB - 1) / HISTB;
    const int e0 = hb * chunk;
    const int e1 = min(E, e0 + chunk);
    for (int e = e0 + tid; e < e1; e += 256) atomicAdd(&lh[dst[e] >> BSH], 1);
    __syncthreads();
    for (int j = tid; j < MAXBK; j += 256) {
      int v = lh[j];
      if (v) atomicAdd(&bhist[j], v);
    }
    return;
  }

  // prep role: block-local dtype probe + weight convert
  __shared__ int cnt_s;
  if (tid == 0) cnt_s = 0;
  __syncthreads();
  int c = 0;
  for (int j = tid; j < 4096; j += 256) {
    u32 e = (((const u16*)W1)[j] >> 7) & 0xFFu;
    if (e >= 100u && e <= 130u) c++;
  }
  atomicAdd(&cnt_s, c);
  __syncthreads();
  const int m = (cnt_s < 3328) ? 1 : 0;  // 1 = fp32
  if (blockIdx.x == 0 && tid == 0) *mode = m;

  int i = blockIdx.x * 256 + tid;
  if (i < 24768) {
    int j = i;
    const void* src;
    u16* dstp;
    int sidx, didx;
    if (j < 16384) {
      // W1f fragment order: j = ((nt*4+s)*64 + lane)*8 + jj
      int jj = j & 7, ln = (j >> 3) & 63, s = (j >> 9) & 3, nt = j >> 11;
      int k = s * 32 + (ln >> 4) * 8 + jj;   // K index
      int nn = nt * 16 + (ln & 15);          // N index
      src = W1; dstp = W1f; sidx = k * 128 + nn; didx = j;
    } else if ((j -= 16384) < 128) {
      src = b1; dstp = ob1; sidx = j; didx = j;
    } else if ((j -= 128) < 8192) {
      int nn = j >> 7, k = j & 127;               // W2t[n][k] = W2[k][n]
      src = W2; dstp = W2t; sidx = k * 64 + nn; didx = j;
    } else {
      j -= 8192;
      src = b2; dstp = ob2; sidx = j; didx = j;
    }
    dstp[didx] = m ? f2b(((const float*)src)[sidx]) : ((const u16*)src)[sidx];
  }
}

// ---- part_k: radix partition edges by dst bucket into tmp (sequential runs) ----

__global__ __launch_bounds__(256) void part_k(const int* __restrict__ src,
                                              const int* __restrict__ dst,
                                              const int* __restrict__ bhist,
                                              int* __restrict__ boff,
                                              int2* __restrict__ tmp,
                                              int E, int NBK) {
  __shared__ int ls[SEG];
  __shared__ int ld_[SEG];
  __shared__ int lh[MAXBK];
  __shared__ int base_[MAXBK];
  __shared__ int bsl[MAXBK];
  const int tid = threadIdx.x;

  // exclusive scan of bhist -> bsl (256 threads, 256 entries)
  int ov = (tid < NBK) ? bhist[tid] : 0;
  bsl[tid] = ov;
  __syncthreads();
#pragma unroll
  for (int off = 1; off < 256; off <<= 1) {
    int add = (tid >= off) ? bsl[tid - off] : 0;
    __syncthreads();
    bsl[tid] += add;
    __syncthreads();
  }
  bsl[tid] -= ov;  // exclusive
  if (tid < MAXBK) lh[tid] = 0;
  __syncthreads();

  const int e0 = blockIdx.x * SEG;
  const int len = min(SEG, E - e0);
  for (int j = tid; j < len; j += 256) {
    int s = src[e0 + j];
    int d = dst[e0 + j];
    ls[j] = s;
    ld_[j] = d;
    atomicAdd(&lh[d >> BSH], 1);
  }
  __syncthreads();
  if (tid < NBK) {
    int hh = lh[tid];
    base_[tid] = hh ? bsl[tid] + atomicAdd(&boff[tid], hh) : 0;
    lh[tid] = 0;  // reuse as rank counter
  }
  __syncthreads();
  for (int j = tid; j < len; j += 256) {
    int d = ld_[j];
    int bk = d >> BSH;
    int r = atomicAdd(&lh[bk], 1);
    tmp[base_[bk] + r] = make_int2(ls[j], d);
  }
}

// ---- nbuild_k: one block per bucket (R12-proven) ----

__global__ __launch_bounds__(256) void nbuild_k(const int2* __restrict__ tmp,
                                                const int* __restrict__ bhist,
                                                float* __restrict__ dinv,
                                                int4* __restrict__ ninfo,
                                                int* __restrict__ spI,
                                                int np, int NBK) {
  __shared__ int bsl[MAXBK];
  __shared__ int cntl[1 << BSH];
  __shared__ int curl[1 << BSH];
  __shared__ int sc2[256];
  const int tid = threadIdx.x;
  const int b = blockIdx.x;

  int ov = (tid < NBK) ? bhist[tid] : 0;
  bsl[tid] = ov;
  __syncthreads();
#pragma unroll
  for (int off = 1; off < 256; off <<= 1) {
    int add = (tid >= off) ? bsl[tid - off] : 0;
    __syncthreads();
    bsl[tid] += add;
    __syncthreads();
  }
  bsl[tid] -= ov;
  cntl[tid] = 0;
  cntl[tid + 256] = 0;
  curl[tid] = 0;
  curl[tid + 256] = 0;
  __syncthreads();

  const int bs = bsl[b];
  const int be = bs + bhist[b];
  const int lo = b << BSH;

  for (int e = bs + tid; e < be; e += 256) {
    int2 p = tmp[e];
    atomicAdd(&cntl[p.y & BMSK], 1);
  }
  __syncthreads();

  const int c0 = cntl[2 * tid];
  const int c1 = cntl[2 * tid + 1];
  const int s2 = c0 + c1;
  sc2[tid] = s2;
  __syncthreads();
#pragma unroll
  for (int off = 1; off < 256; off <<= 1) {
    int add = (tid >= off) ? sc2[tid - off] : 0;
    __syncthreads();
    sc2[tid] += add;
    __syncthreads();
  }
  const int excl = sc2[tid] - s2;
  const int e0n = excl;
  const int e1n = excl + c0;

  {
    int i0 = lo + 2 * tid;
    if (i0 < np) {
      float dv = rsqrtf((float)c0 + 1.0f);
      dinv[i0] = dv;
      ninfo[i0] = make_int4(bs + e0n, c0, __float_as_int(dv), 0);
    }
    int i1 = i0 + 1;
    if (i1 < np) {
      float dv = rsqrtf((float)c1 + 1.0f);
      dinv[i1] = dv;
      ninfo[i1] = make_int4(bs + e1n, c1, __float_as_int(dv), 0);
    }
  }
  cntl[2 * tid] = e0n;
  cntl[2 * tid + 1] = e1n;
  __syncthreads();

  for (int e = bs + tid; e < be; e += 256) {
    int2 p = tmp[e];
    int loc = p.y & BMSK;
    int r = atomicAdd(&curl[loc], 1);
    spI[bs + cntl[loc] + r] = p.x;
  }
}

// ---- gemm1: h = x @ W1, no LDS. B from fragment-ordered W1f (coalesced 1KB
// wave-loads, L1-broadcast across waves); A direct from global with 2-deep
// tile prefetch (A(t+1) in flight under tile t's MFMA/store phase). ----

__device__ __forceinline__ void loadA(const void* Araw, int arow, bool rok,
                                      int lq, int mcv, bf16x8 a[4]) {
  if (mcv) {
    const float* xr = (const float*)Araw + (size_t)arow * 128 + lq * 8;
#pragma unroll
    for (int s = 0; s < 4; ++s) {
      uint4 u = make_uint4(0u, 0u, 0u, 0u);
      if (rok) {
        float4 f0 = *(const float4*)(xr + s * 32);
        float4 f1 = *(const float4*)(xr + s * 32 + 4);
        u.x = pk2(f0.x, f0.y);
        u.y = pk2(f0.z, f0.w);
        u.z = pk2(f1.x, f1.y);
        u.w = pk2(f1.z, f1.w);
      }
      a[s] = *(const bf16x8*)&u;
    }
  } else {
    const u16* xr = (const u16*)Araw + (size_t)arow * 128 + lq * 8;
#pragma unroll
    for (int s = 0; s < 4; ++s) {
      uint4 u = rok ? *(const uint4*)(xr + s * 32) : make_uint4(0u, 0u, 0u, 0u);
      a[s] = *(const bf16x8*)&u;
    }
  }
}

__global__ __launch_bounds__(256) void gemm1_k(const void* __restrict__ Araw,
                                               const u16* __restrict__ W1f,
                                               u16* __restrict__ hout, int M,
                                               const int* __restrict__ mode) {
  const int tid = threadIdx.x;
  const int mcv = *mode;
  const int wv = tid >> 6, lane = tid & 63, lr = lane & 15, lq = lane >> 4;
  const int ntiles = (M + 63) >> 6;

  int t = blockIdx.x;
  if (t >= ntiles) return;

  bf16x8 a_cur[4], a_nxt[4];
  {
    const int arow = t * 64 + wv * 16 + lr;
    loadA(Araw, arow, arow < M, lq, mcv, a_cur);
  }

  for (; t < ntiles; t += GEMMB) {
    const int tn = t + GEMMB;
    if (tn < ntiles) {
      const int arow = tn * 64 + wv * 16 + lr;
      loadA(Araw, arow, arow < M, lq, mcv, a_nxt);   // in flight under MFMAs
    }

    const int r0 = t * 64;
#pragma unroll
    for (int nt = 0; nt < 8; ++nt) {
      f32x4 acc = {0.f, 0.f, 0.f, 0.f};
#pragma unroll
      for (int s = 0; s < 4; ++s) {
        bf16x8 b = *(const bf16x8*)&W1f[(size_t)(((nt << 2) | s) << 6 | lane) * 8];
        acc = __builtin_amdgcn_mfma_f32_16x16x32_bf16(a_cur[s], b, acc, 0, 0, 0);
      }
#pragma unroll
      for (int r = 0; r < 4; ++r) {
        int row = r0 + wv * 16 + lq * 4 + r;
        if (row < M) hout[(size_t)row * 128 + nt * 16 + lr] = f2b(acc[r]);
      }
    }
#pragma unroll
    for (int s = 0; s < 4; ++s) a_cur[s] = a_nxt[s];
  }
}

// ---- fusedB: gather-aggregate h (16 nodes/block, quarter-wave, unroll-4)
//      -> +b1, relu -> LDS tile -> MFMA W2t -> g[N,64] ----   (R12-proven)

__global__ __launch_bounds__(256) void fusedB_k(const u16* __restrict__ h,
                                                const int* __restrict__ spI,
                                                const int4* __restrict__ ninfo,
                                                const float* __restrict__ dinv,
                                                const u16* __restrict__ b1,
                                                const u16* __restrict__ W2t,
                                                u16* __restrict__ g, int n) {
  __shared__ __align__(16) u16 As[16 * 136];
  const int tid = threadIdx.x, wv = tid >> 6, lane = tid & 63;
  const int lq = lane >> 4, lr = lane & 15;
  const int base = blockIdx.x * 16;
  const int i = base + wv * 4 + lq;
  const bool valid = (i < n);

  int start = 0, c = 0;
  float di = 0.f;
  if (valid) {
    int4 ni = ninfo[i];
    start = ni.x;
    c = ni.y;
    di = __int_as_float(ni.z);
  }
  float acc[8];
  {
    uint4 v = valid ? *(const uint4*)(h + (size_t)i * 128 + lr * 8)
                    : make_uint4(0u, 0u, 0u, 0u);
    float f[8];
    dec8(v, f);
#pragma unroll
    for (int j = 0; j < 8; ++j) acc[j] = f[j] * di;
  }
  const int bl = lq * 16;
  for (int bs = 0; __any(bs < c); bs += 16) {
    int m = c - bs;
    m = m < 0 ? 0 : (m > 16 ? 16 : m);
    int s = 0;
    float dv = 0.f;
    if (lr < m) {
      s = spI[start + bs + lr];
      dv = dinv[s];
    }
    int mmw = m;
    mmw = max(mmw, __shfl_xor(mmw, 16));
    mmw = max(mmw, __shfl_xor(mmw, 32));
    for (int e = 0; e < mmw; e += 4) {
      int s0 = __shfl(s, bl + e), s1 = __shfl(s, bl + e + 1);
      int s2 = __shfl(s, bl + e + 2), s3 = __shfl(s, bl + e + 3);
      float d0 = __shfl(dv, bl + e);
      float d1 = __shfl(dv, bl + e + 1);
      float d2 = __shfl(dv, bl + e + 2);
      float d3 = __shfl(dv, bl + e + 3);
      uint4 v0 = *(const uint4*)(h + (size_t)s0 * 128 + lr * 8);
      uint4 v1 = *(const uint4*)(h + (size_t)s1 * 128 + lr * 8);
      uint4 v2 = *(const uint4*)(h + (size_t)s2 * 128 + lr * 8);
      uint4 v3 = *(const uint4*)(h + (size_t)s3 * 128 + lr * 8);
      fma8(v0, d0, acc);
      fma8(v1, d1, acc);
      fma8(v2, d2, acc);
      fma8(v3, d3, acc);
    }
  }
  {
    uint4 bv = *(const uint4*)(b1 + lr * 8);
    float bf[8];
    dec8(bv, bf);
    float o[8];
#pragma unroll
    for (int j = 0; j < 8; ++j) o[j] = fmaxf(fmaf(acc[j], di, bf[j]), 0.f);
    uint4 ov;
    ov.x = pk2(o[0], o[1]);
    ov.y = pk2(o[2], o[3]);
    ov.z = pk2(o[4], o[5]);
    ov.w = pk2(o[6], o[7]);
    *(uint4*)&As[(wv * 4 + lq) * 136 + lr * 8] = ov;
  }
  __syncthreads();

  bf16x8 a[4];
#pragma unroll
  for (int s = 0; s < 4; ++s)
    a[s] = *(const bf16x8*)&As[lr * 136 + s * 32 + lq * 8];
  {
    const int nt = wv;
    f32x4 acc4 = {0.f, 0.f, 0.f, 0.f};
#pragma unroll
    for (int s = 0; s < 4; ++s) {
      bf16x8 b = *(const bf16x8*)&W2t[(nt * 16 + lr) * 128 + s * 32 + lq * 8];
      acc4 = __builtin_amdgcn_mfma_f32_16x16x32_bf16(a[s], b, acc4, 0, 0, 0);
    }
#pragma unroll
    for (int r = 0; r < 4; ++r) {
      int row = base + lq * 4 + r;
      if (row < n) g[(size_t)row * 64 + nt * 16 + lr] = f2b(acc4[r]);
    }
  }
}

// ---- agg2: oct-wave over g, 8 nodes/wave, unroll-4 ----   (R12-proven)

__global__ __launch_bounds__(256) void agg2_k(const u16* __restrict__ g,
                                              const int* __restrict__ spI,
                                              const int4* __restrict__ ninfo,
                                              const float* __restrict__ dinv,
                                              const u16* __restrict__ b2,
                                              void* __restrict__ outv, int n,
                                              const int* __restrict__ mode) {
  const int lane = threadIdx.x & 63;
  const int o8 = lane >> 3, l8 = lane & 7;
  const int i = blockIdx.x * 32 + (threadIdx.x >> 6) * 8 + o8;
  const bool valid = (i < n);

  int start = 0, c = 0;
  float di = 0.f;
  if (valid) {
    int4 ni = ninfo[i];
    start = ni.x;
    c = ni.y;
    di = __int_as_float(ni.z);
  }
  float acc[8];
  {
    uint4 v = valid ? *(const uint4*)(g + (size_t)i * 64 + l8 * 8)
                    : make_uint4(0u, 0u, 0u, 0u);
    float f[8];
    dec8(v, f);
#pragma unroll
    for (int j = 0; j < 8; ++j) acc[j] = f[j] * di;
  }
  const int bl = o8 * 8;
  for (int base = 0; __any(base < c); base += 8) {
    int m = c - base;
    m = m < 0 ? 0 : (m > 8 ? 8 : m);
    int s = 0;
    float dv = 0.f;
    if (l8 < m) {
      s = spI[start + base + l8];
      dv = dinv[s];
    }
    int mmw = m;
    mmw = max(mmw, __shfl_xor(mmw, 8));
    mmw = max(mmw, __shfl_xor(mmw, 16));
    mmw = max(mmw, __shfl_xor(mmw, 32));
    for (int e = 0; e < mmw; e += 4) {
      int s0 = __shfl(s, bl + e), s1 = __shfl(s, bl + e + 1);
      int s2 = __shfl(s, bl + e + 2), s3 = __shfl(s, bl + e + 3);
      float d0 = __shfl(dv, bl + e);
      float d1 = __shfl(dv, bl + e + 1);
      float d2 = __shfl(dv, bl + e + 2);
      float d3 = __shfl(dv, bl + e + 3);
      uint4 v0 = *(const uint4*)(g + (size_t)s0 * 64 + l8 * 8);
      uint4 v1 = *(const uint4*)(g + (size_t)s1 * 64 + l8 * 8);
      uint4 v2 = *(const uint4*)(g + (size_t)s2 * 64 + l8 * 8);
      uint4 v3 = *(const uint4*)(g + (size_t)s3 * 64 + l8 * 8);
      fma8(v0, d0, acc);
      fma8(v1, d1, acc);
      fma8(v2, d2, acc);
      fma8(v3, d3, acc);
    }
  }
  if (valid) {
    uint4 bv = *(const uint4*)(b2 + l8 * 8);
    float bf[8];
    dec8(bv, bf);
    float o[8];
#pragma unroll
    for (int j = 0; j < 8; ++j) o[j] = fmaf(acc[j], di, bf[j]);
    if (*mode) {
      float* op = (float*)outv + (size_t)i * 64 + l8 * 8;
      *(float4*)op = make_float4(o[0], o[1], o[2], o[3]);
      *(float4*)(op + 4) = make_float4(o[4], o[5], o[6], o[7]);
    } else {
      uint4 ov;
      ov.x = pk2(o[0], o[1]);
      ov.y = pk2(o[2], o[3]);
      ov.z = pk2(o[4], o[5]);
      ov.w = pk2(o[6], o[7]);
      *(uint4*)((u16*)outv + (size_t)i * 64 + l8 * 8) = ov;
    }
  }
}

// ================= launch =================

extern "C" void kernel_launch(void* const* d_in, const int* in_sizes, int n_in,
                              void* d_out, int out_size, void* d_ws, size_t ws_size,
                              hipStream_t stream) {
  const void* x_raw  = d_in[0];
  const int*  ei     = (const int*)d_in[1];
  const void* W1_raw = d_in[2];
  const void* b1_raw = d_in[3];
  const void* W2_raw = d_in[4];
  const void* b2_raw = d_in[5];

  const int N = in_sizes[0] / 128;
  const int E = in_sizes[1] / 2;
  const int NP = ((N + 255) / 256) * 256;
  const int NBK = (NP + (1 << BSH) - 1) >> BSH;   // buckets (<=256 for N<=131072)
  const int PREPB = (24768 + 255) / 256;          // 97 prep blocks

  char* ws = (char*)d_ws;
  size_t off = 0;
  auto alloc = [&](size_t bytes) -> void* {
    void* p = ws + off;
    off = (off + bytes + 255) & ~(size_t)255;
    return p;
  };
  int*   mode    = (int*)alloc(4);
  int*   bz      = (int*)alloc((size_t)2 * MAXBK * 4);  // bhist | boff
  int*   bhist   = bz;
  int*   boff    = bz + MAXBK;
  float* dinv    = (float*)alloc((size_t)NP * 4);
  int4*  ninfo   = (int4*)alloc((size_t)NP * 16);
  int*   spI     = (int*)alloc((size_t)E * 4);
  int2*  tmp     = (int2*)alloc((size_t)E * 8);
  u16*   W1f     = (u16*)alloc((size_t)128 * 128 * 2);
  u16*   b1b     = (u16*)alloc(128 * 2);
  u16*   W2t     = (u16*)alloc((size_t)64 * 128 * 2);
  u16*   b2b     = (u16*)alloc(64 * 2);
  u16*   h       = (u16*)alloc((size_t)N * 128 * 2);
  u16*   g       = (u16*)alloc((size_t)N * 64 * 2);

  const int pb = (E + SEG - 1) / SEG;

  hipMemsetAsync(bz, 0, (size_t)2 * MAXBK * 4, stream);
  prep_hist_k<<<PREPB + HISTB, 256, 0, stream>>>(W1_raw, b1_raw, W2_raw, b2_raw,
                                                 W1f, b1b, W2t, b2b, mode,
                                                 ei + E, bhist, E, PREPB);
  part_k<<<pb, 256, 0, stream>>>(ei, ei + E, bhist, boff, tmp, E, NBK);
  nbuild_k<<<NBK, 256, 0, stream>>>(tmp, bhist, dinv, ninfo, spI, NP, NBK);
  gemm1_k<<<GEMMB, 256, 0, stream>>>(x_raw, W1f, h, N, mode);
  fusedB_k<<<(N + 15) / 16, 256, 0, stream>>>(h, spI, ninfo, dinv, b1b, W2t, g, N);
  agg2_k<<<(N + 31) / 32, 256, 0, stream>>>(g, spI, ninfo, dinv, b2b, d_out, N, mode);
}